// Round 4
// baseline (183.319 us; speedup 1.0000x reference)
//
#include <hip/hip_runtime.h>

#define BB 2
#define CC 2
#define NN 1024
#define HH 8
#define BCHN 32
#define SVN  (BCHN*NN)       // 32768
#define LOG2E 1.44269504f
#define X1S 520              // x1 LDS row stride in f16 (16B-aligned, bank-staggered)

typedef _Float16 f16x8 __attribute__((ext_vector_type(8)));
typedef _Float16 f16x4 __attribute__((ext_vector_type(4)));
typedef __fp16 h16x2 __attribute__((ext_vector_type(2)));   // cvt_pkrtz native type
typedef float f32x4 __attribute__((ext_vector_type(4)));

__device__ __forceinline__ float fexp2(float x) {
  float r; asm("v_exp_f32 %0, %1" : "=v"(r) : "v"(x)); return r;
}

// ---------------- Fused layer-1 projection + prep (one dispatch, no intra-deps) ----------
__global__ __launch_bounds__(256) void proj1_fused(
    const float* __restrict__ x, const int* __restrict__ adj,
    const float* __restrict__ w1, const float* __restrict__ w2,
    const float* __restrict__ asrc, const float* __restrict__ adst,
    _Float16* __restrict__ w2T, unsigned long long* __restrict__ bmg,
    _Float16* __restrict__ HpT, float* __restrict__ s_out, float* __restrict__ d_out)
{
  __shared__ union {
    __align__(16) _Float16 tile[64*72];                 // transpose staging (aux)
    struct { float sp[4][32]; float sd[4][32]; } pr;    // proj reductions
  } sm;
  const int bx = blockIdx.x;
  const int t = threadIdx.x;
  const int w = t >> 6, lane = t & 63;
  const int colr = lane & 15, quad = lane >> 4;

  if (bx < 1024) {
    // ---- projection: C[32 rows][64 f] = x[rows][64] @ w1[c,h][64k][64f] ----
    const int bch = bx & 31;
    const int row0 = (bx >> 5) * 32;
    const int h = bch & 7; const int bc = bch >> 3; const int c = bc & 1;

    const float* Ar0 = x + ((size_t)bc*NN + row0 + colr)*64;
    const float* Ar1 = Ar0 + (size_t)16*64;
    const float* Bw  = w1 + ((size_t)(c*HH + h))*64*64 + w*16 + colr;  // column f, stride 64

    f32x4 acc0 = {0.f,0.f,0.f,0.f}, acc1 = {0.f,0.f,0.f,0.f};
    #pragma unroll
    for (int kb = 0; kb < 64; kb += 32) {
      const float4 pa0 = *(const float4*)(Ar0 + kb + quad*8);
      const float4 pa1 = *(const float4*)(Ar0 + kb + quad*8 + 4);
      const float4 pb0 = *(const float4*)(Ar1 + kb + quad*8);
      const float4 pb1 = *(const float4*)(Ar1 + kb + quad*8 + 4);
      float bv[8];
      #pragma unroll
      for (int j = 0; j < 8; ++j) bv[j] = Bw[(size_t)(kb + quad*8 + j)*64];
      f16x8 a0, a1, bf;
      a0[0]=(_Float16)pa0.x; a0[1]=(_Float16)pa0.y; a0[2]=(_Float16)pa0.z; a0[3]=(_Float16)pa0.w;
      a0[4]=(_Float16)pa1.x; a0[5]=(_Float16)pa1.y; a0[6]=(_Float16)pa1.z; a0[7]=(_Float16)pa1.w;
      a1[0]=(_Float16)pb0.x; a1[1]=(_Float16)pb0.y; a1[2]=(_Float16)pb0.z; a1[3]=(_Float16)pb0.w;
      a1[4]=(_Float16)pb1.x; a1[5]=(_Float16)pb1.y; a1[6]=(_Float16)pb1.z; a1[7]=(_Float16)pb1.w;
      #pragma unroll
      for (int j = 0; j < 8; ++j) bf[j] = (_Float16)bv[j];
      acc0 = __builtin_amdgcn_mfma_f32_16x16x32_f16(a0, bf, acc0, 0, 0, 0);
      acc1 = __builtin_amdgcn_mfma_f32_16x16x32_f16(a1, bf, acc1, 0, 0, 0);
    }

    const float af  = asrc[(c*HH + h)*64 + w*16 + colr];
    const float bf_ = adst[(c*HH + h)*64 + w*16 + colr];
    _Float16* HT = HpT + ((size_t)bch*64 + w*16 + colr)*NN + row0;

    #pragma unroll
    for (int mt = 0; mt < 2; ++mt) {
      const f32x4 a = mt ? acc1 : acc0;
      f16x4 hv;
      #pragma unroll
      for (int i = 0; i < 4; ++i) {
        const float v = a[i];
        hv[i] = (_Float16)v;
        const float ex = __expf(2.f*v);
        const float th = 1.f - 2.f/(ex + 1.f);         // tanh(v)
        float ps = th * af, pd = th * bf_;
        #pragma unroll
        for (int off = 1; off < 16; off <<= 1) {
          ps += __shfl_xor(ps, off);
          pd += __shfl_xor(pd, off);
        }
        if (colr == 0) {
          sm.pr.sp[w][mt*16 + quad*4 + i] = ps;
          sm.pr.sd[w][mt*16 + quad*4 + i] = pd;
        }
      }
      *(f16x4*)(HT + mt*16 + quad*4) = hv;
    }
    __syncthreads();
    if (t < 32) {
      const float sv = sm.pr.sp[0][t] + sm.pr.sp[1][t] + sm.pr.sp[2][t] + sm.pr.sp[3][t];
      const float dv = sm.pr.sd[0][t] + sm.pr.sd[1][t] + sm.pr.sd[2][t] + sm.pr.sd[3][t];
      s_out[bch*NN + row0 + t] = sv * LOG2E;   // log2e-scaled: attn uses raw v_exp_f32
      d_out[bch*NN + row0 + t] = dv * LOG2E;
    }
  } else if (bx < 1152) {
    // ---- w2 transpose -> w2T[ch][64 f][512 k] ----
    const int u = bx - 1024;
    const int ch = u >> 3, k0 = (u & 7)*64;
    const float* src = w2 + ((size_t)ch*512 + k0)*64;
    #pragma unroll
    for (int j = 0; j < 4; ++j) {
      const int uu = t + j*256;
      const int k = uu >> 4, seg = uu & 15;
      const float4 v = ((const float4*)src)[(size_t)k*16 + seg];
      sm.tile[(seg*4+0)*72 + k] = (_Float16)v.x;
      sm.tile[(seg*4+1)*72 + k] = (_Float16)v.y;
      sm.tile[(seg*4+2)*72 + k] = (_Float16)v.z;
      sm.tile[(seg*4+3)*72 + k] = (_Float16)v.w;
    }
    __syncthreads();
    _Float16* dst = w2T + (size_t)ch*64*512 + k0;
    #pragma unroll
    for (int j = 0; j < 2; ++j) {
      const int uu = t + j*256;
      const int f = uu >> 3, seg = uu & 7;
      const f16x8 o = *(const f16x8*)&sm.tile[f*72 + seg*8];
      *(f16x8*)(dst + (size_t)f*512 + seg*8) = o;
    }
  } else {
    // ---- mask build: 8 independent loads per batch ----
    const int g = (bx - 1152)*4 + w;     // 1024 wave-units
    const int base = g*32;
    #pragma unroll
    for (int jb = 0; jb < 4; ++jb) {
      int vals[8];
      #pragma unroll
      for (int i = 0; i < 8; ++i) {
        const int idx = base + jb*8 + i;
        const int b = idx >> 14;
        const int n = (idx >> 4) & (NN - 1);
        const int wd = idx & 15;
        vals[i] = adj[((size_t)b*NN + n)*NN + wd*64 + lane];
      }
      #pragma unroll
      for (int i = 0; i < 8; ++i) {
        const int idx = base + jb*8 + i;
        const int n = (idx >> 4) & (NN - 1);
        const int m = (idx & 15)*64 + lane;
        const unsigned long long bits = __ballot((vals[i] != 0) || (m == n));
        if (lane == 0) bmg[idx] = bits;
      }
    }
  }
}

// ---------------- Monster: all-heads attention for a 16-row tile, fused with next stage ----
// 512 threads = 8 waves; wave h = head h; block (bc, rt) owns rows rt*16..+15 of bc.
// Wave h streams HpT[bc*8+h] over the FULL k range -> row-sums are wave-local (ones-MFMA).
// LAYER 1: normalize+ELU -> x1 tile in LDS [16][512] -> proj2 per head -> HpT2, s2, d2.
// LAYER 2: normalize -> LDS f32 atomic mean over heads -> final f32 output.
// grid (x=bc=4, y=rt=64): linear%8 = (bc+4*rt)%8 in {bc, bc+4} -> each XCD serves one bc.
template<int LAYER>
__global__ __launch_bounds__(512, 2) void attn_monster(
    const _Float16* __restrict__ HpTin, const float* __restrict__ s_arr,
    const float* __restrict__ d_arr, const unsigned long long* __restrict__ bmg,
    const _Float16* __restrict__ w2T, const float* __restrict__ asrc2,
    const float* __restrict__ adst2,
    _Float16* __restrict__ HpT2, float* __restrict__ s2, float* __restrict__ d2,
    float* __restrict__ out)
{
  __shared__ union {
    __align__(16) _Float16 x1[16*X1S];   // 16.6 KB (LAYER 1)
    float mbuf[16*64];                   // 4 KB   (LAYER 2)
  } sm;
  const int bc = blockIdx.x;             // 0..3
  const int r0 = blockIdx.y * 16;        // row tile
  const int t = threadIdx.x;
  const int h = t >> 6;                  // wave = head
  const int lane = t & 63;
  const int colr = lane & 15, quad = lane >> 4;
  const int bch = bc*HH + h;
  const int b = bc >> 1, c = bc & 1;

  if (LAYER == 2) {                      // zero mean buffer before any atomics
    sm.mbuf[t] = 0.f;
    sm.mbuf[t + 512] = 0.f;
    __syncthreads();
  }

  // wave-local maxd over full d[bch]
  const float* dg = d_arr + (size_t)bch*NN;
  const float4* dg4 = (const float4*)dg;
  float mxl = -1e30f;
  #pragma unroll
  for (int j = 0; j < 4; ++j) {
    const float4 v = dg4[lane + 64*j];
    mxl = fmaxf(fmaxf(v.x, v.y), fmaxf(fmaxf(v.z, v.w), mxl));
  }
  #pragma unroll
  for (int off = 1; off < 64; off <<= 1) mxl = fmaxf(mxl, __shfl_xor(mxl, off));
  const float maxd = mxl;

  const int r = r0 + colr;
  const float s = s_arr[(size_t)bch*NN + r];
  const float so = s + maxd;
  const float offs = fmaxf(so, 0.2f*so);       // >= lrelu(s+d) for all d
  const float sA = s - offs, sB = 0.2f*s - offs;

  const unsigned long long* bm = bmg + ((size_t)b*NN + r)*16;
  const _Float16* Bp = HpTin + (size_t)bch*64*NN + quad*8;

  f32x4 acc[4];
  f32x4 accs = {0.f,0.f,0.f,0.f};
  #pragma unroll
  for (int ft = 0; ft < 4; ++ft) acc[ft] = (f32x4){0.f,0.f,0.f,0.f};
  f16x8 ones;
  #pragma unroll
  for (int i = 0; i < 8; ++i) ones[i] = (_Float16)1.f;

  // prefetch ks=0
  f16x8 Bc[4];
  #pragma unroll
  for (int ft = 0; ft < 4; ++ft) Bc[ft] = *(const f16x8*)(Bp + (size_t)(ft*16 + colr)*NN);
  float4 dc0 = *(const float4*)(dg + quad*8);
  float4 dc1 = *(const float4*)(dg + quad*8 + 4);
  unsigned long long mcur = bm[0], mnxt = 0;

  #pragma unroll 2
  for (int kp = 0; kp < 16; ++kp) {            // 16 mask-word pairs = 32 k-steps
    if (kp < 15) mnxt = bm[kp + 1];
    #pragma unroll
    for (int hf = 0; hf < 2; ++hf) {
      const int ks = kp*2 + hf;
      f16x8 Bn[4]; float4 dn0, dn1;
      if (ks < 31) {
        #pragma unroll
        for (int ft = 0; ft < 4; ++ft)
          Bn[ft] = *(const f16x8*)(Bp + (size_t)(ft*16 + colr)*NN + (ks+1)*32);
        dn0 = *(const float4*)(dg + (ks+1)*32 + quad*8);
        dn1 = *(const float4*)(dg + (ks+1)*32 + quad*8 + 4);
      }
      const unsigned mb = (unsigned)((mcur >> (hf*32 + quad*8)) & 0xFFull);
      const float dd[8] = {dc0.x, dc0.y, dc0.z, dc0.w, dc1.x, dc1.y, dc1.z, dc1.w};
      union { f16x8 v; h16x2 hh[4]; } A;
      #pragma unroll
      for (int jp = 0; jp < 4; ++jp) {
        float p[2];
        #pragma unroll
        for (int jj = 0; jj < 2; ++jj) {
          const int j = jp*2 + jj;
          const float dj = dd[j];
          const float l = fmaxf(sA + dj, fmaf(0.2f, dj, sB));  // log2e-scaled domain
          p[jj] = ((mb >> j) & 1u) ? fexp2(l) : 0.f;
        }
        A.hh[jp] = __builtin_amdgcn_cvt_pkrtz(p[0], p[1]);
      }
      #pragma unroll
      for (int ft = 0; ft < 4; ++ft)
        acc[ft] = __builtin_amdgcn_mfma_f32_16x16x32_f16(A.v, Bc[ft], acc[ft], 0, 0, 0);
      accs = __builtin_amdgcn_mfma_f32_16x16x32_f16(A.v, ones, accs, 0, 0, 0);
      if (ks < 31) {
        #pragma unroll
        for (int ft = 0; ft < 4; ++ft) Bc[ft] = Bn[ft];
        dc0 = dn0; dc1 = dn1;
      }
    }
    mcur = mnxt;
  }

  // accs[i] = full-k row sum for row q = quad*4+i (identical across colr)
  float inv[4];
  #pragma unroll
  for (int i = 0; i < 4; ++i) inv[i] = 1.f / accs[i];

  if (LAYER == 1) {
    // x1 = elu(attn_out) -> LDS f16 tile [16][8*64], padded stride
    #pragma unroll
    for (int ft = 0; ft < 4; ++ft)
      #pragma unroll
      for (int i = 0; i < 4; ++i) {
        float v = acc[ft][i] * inv[i];
        v = v > 0.f ? v : expm1f(v);
        sm.x1[(quad*4 + i)*X1S + h*64 + ft*16 + colr] = (_Float16)v;
      }
    __syncthreads();

    // proj2 for head h2 = h: C2[16 rows][64 f] = x1[16][512] @ w2T[c,h][64][512]^T
    const _Float16* Bw = w2T + (size_t)(c*HH + h)*64*512 + quad*8;
    f32x4 acc2[4];
    #pragma unroll
    for (int ft = 0; ft < 4; ++ft) acc2[ft] = (f32x4){0.f,0.f,0.f,0.f};
    f16x8 Wc[4];
    #pragma unroll
    for (int ft = 0; ft < 4; ++ft) Wc[ft] = *(const f16x8*)(Bw + (size_t)(ft*16 + colr)*512);
    #pragma unroll 4
    for (int k2 = 0; k2 < 16; ++k2) {
      f16x8 Wn[4];
      if (k2 < 15) {
        #pragma unroll
        for (int ft = 0; ft < 4; ++ft)
          Wn[ft] = *(const f16x8*)(Bw + (size_t)(ft*16 + colr)*512 + (k2+1)*32);
      }
      const f16x8 Af = *(const f16x8*)&sm.x1[colr*X1S + k2*32 + quad*8];
      #pragma unroll
      for (int ft = 0; ft < 4; ++ft)
        acc2[ft] = __builtin_amdgcn_mfma_f32_16x16x32_f16(Af, Wc[ft], acc2[ft], 0, 0, 0);
      if (k2 < 15) {
        #pragma unroll
        for (int ft = 0; ft < 4; ++ft) Wc[ft] = Wn[ft];
      }
    }

    // epilogue: tanh scores (in-wave f-reduction) + transposed HpT2 write
    float af[4], bfv[4];
    #pragma unroll
    for (int ft = 0; ft < 4; ++ft) {
      af[ft]  = asrc2[(c*HH + h)*64 + ft*16 + colr];
      bfv[ft] = adst2[(c*HH + h)*64 + ft*16 + colr];
    }
    #pragma unroll
    for (int i = 0; i < 4; ++i) {
      float ps = 0.f, pd = 0.f;
      #pragma unroll
      for (int ft = 0; ft < 4; ++ft) {
        const float v = acc2[ft][i];
        const float ex = __expf(2.f*v);
        const float th = 1.f - 2.f/(ex + 1.f);
        ps += th * af[ft]; pd += th * bfv[ft];
      }
      #pragma unroll
      for (int off = 1; off < 16; off <<= 1) {
        ps += __shfl_xor(ps, off);
        pd += __shfl_xor(pd, off);
      }
      if (colr == 0) {
        s2[(size_t)bch*NN + r0 + quad*4 + i] = ps * LOG2E;
        d2[(size_t)bch*NN + r0 + quad*4 + i] = pd * LOG2E;
      }
    }
    #pragma unroll
    for (int ft = 0; ft < 4; ++ft) {
      f16x4 hv;
      #pragma unroll
      for (int i = 0; i < 4; ++i) hv[i] = (_Float16)acc2[ft][i];
      *(f16x4*)(HpT2 + ((size_t)bch*64 + ft*16 + colr)*NN + r0 + quad*4) = hv;
    }
  } else {
    // mean over heads via LDS f32 atomics, then final write
    #pragma unroll
    for (int ft = 0; ft < 4; ++ft)
      #pragma unroll
      for (int i = 0; i < 4; ++i)
        atomicAdd(&sm.mbuf[(quad*4 + i)*64 + ft*16 + colr], acc[ft][i] * inv[i]);
    __syncthreads();
    const int q = t >> 5;                // thread t -> row q, features (t*2)&63
    const int f = (t*2) & 63;
    const float m0 = sm.mbuf[q*64 + f], m1 = sm.mbuf[q*64 + f + 1];
    float2 ov = {m0 * 0.125f, m1 * 0.125f};
    *(float2*)(out + ((size_t)bc*NN + r0 + q)*64 + f) = ov;
  }
}

extern "C" void kernel_launch(void* const* d_in, const int* in_sizes, int n_in,
                              void* d_out, int out_size, void* d_ws, size_t ws_size,
                              hipStream_t stream)
{
  const float* x   = (const float*)d_in[0];
  const int*   adj = (const int*)d_in[1];
  const float* w1  = (const float*)d_in[2];
  const float* as1 = (const float*)d_in[3];
  const float* ad1 = (const float*)d_in[4];
  const float* w2  = (const float*)d_in[5];
  const float* as2 = (const float*)d_in[6];
  const float* ad2 = (const float*)d_in[7];

  char* w8 = (char*)d_ws;
  _Float16* HpT  = (_Float16*)(w8);                         // 4 MB  [bch][64][N]
  _Float16* HpT2 = (_Float16*)(w8 + (4u<<20));              // 4 MB  [bch][64][N]
  _Float16* w2T  = (_Float16*)(w8 + (8u<<20));              // 1 MB  [ch][64][512]
  float* s_v  = (float*)(w8 + (10u<<20));                   // 128 KB (log2e-scaled)
  float* d_v  = (float*)(w8 + (10u<<20) + SVN*4);           // 128 KB
  float* s2_v = (float*)(w8 + (10u<<20) + SVN*8);           // 128 KB
  float* d2_v = (float*)(w8 + (10u<<20) + SVN*12);          // 128 KB
  unsigned long long* bmg = (unsigned long long*)(w8 + (10u<<20) + SVN*16);  // 256 KB

  proj1_fused<<<1408, 256, 0, stream>>>(x, adj, w1, w2, as1, ad1, w2T, bmg, HpT, s_v, d_v);
  attn_monster<1><<<dim3(4, 64), 512, 0, stream>>>(HpT, s_v, d_v, bmg, w2T, as2, ad2,
                                                   HpT2, s2_v, d2_v, (float*)d_out);
  attn_monster<2><<<dim3(4, 64), 512, 0, stream>>>(HpT2, s2_v, d2_v, bmg, w2T, as2, ad2,
                                                   HpT2, s2_v, d2_v, (float*)d_out);
}